// Round 1
// baseline (844.612 us; speedup 1.0000x reference)
//
#include <hip/hip_runtime.h>
#include <hip/hip_bf16.h>

// ---------------- problem constants ----------------
constexpr int N_NODES  = 50000;
constexpr int N_EDGES  = 800000;
constexpr int N_GRAPHS = 512;
constexpr int F_IN     = 128;
constexpr int HID      = 256;
constexpr int NPAD     = 50048;   // 782*64, padded row count so GEMM needs no load guards

// ---------------- small helpers ----------------
template<int V> struct VecPick;
template<> struct VecPick<2>{ using T = float2; };
template<> struct VecPick<4>{ using T = float4; };

// ---------------- degree histogram ----------------
__global__ void deg_kernel(const int* __restrict__ dst, int* __restrict__ deg) {
    int e = blockIdx.x * blockDim.x + threadIdx.x;
    if (e >= N_EDGES) return;
    atomicAdd(&deg[dst[e]], 1);
}

// dis[i] = rsqrt(deg_in[i] + 1)  (self loop added)
__global__ void dis_kernel(const int* __restrict__ deg, float* __restrict__ dis) {
    int i = blockIdx.x * blockDim.x + threadIdx.x;
    if (i >= N_NODES) return;
    dis[i] = rsqrtf((float)deg[i] + 1.0f);
}

// single-block exclusive scan over deg -> row_start (and cursor copy)
__global__ void scan_kernel(const int* __restrict__ deg, int* __restrict__ row_start,
                            int* __restrict__ cursor, int n) {
    __shared__ int sm[1024];
    __shared__ int carry_s;
    const int t = threadIdx.x;
    if (t == 0) carry_s = 0;
    __syncthreads();
    for (int base = 0; base < n; base += 1024) {
        int i = base + t;
        int v = (i < n) ? deg[i] : 0;
        sm[t] = v;
        __syncthreads();
        for (int off = 1; off < 1024; off <<= 1) {
            int add = (t >= off) ? sm[t - off] : 0;
            __syncthreads();
            sm[t] += add;
            __syncthreads();
        }
        int carry = carry_s;
        int excl  = carry + sm[t] - v;
        if (i < n) { row_start[i] = excl; cursor[i] = excl; }
        __syncthreads();                 // all reads of carry_s done
        if (t == 1023) carry_s = carry + sm[1023];
        __syncthreads();
    }
    if (t == 0) row_start[n] = carry_s;
}

// scatter edges into CSR (by dst), precompute per-edge weight dis[src]*dis[dst]
__global__ void fill_csr(const int* __restrict__ src, const int* __restrict__ dst,
                         const float* __restrict__ dis, int* __restrict__ cursor,
                         int* __restrict__ csr_src, float* __restrict__ csr_w) {
    int e = blockIdx.x * blockDim.x + threadIdx.x;
    if (e >= N_EDGES) return;
    int s = src[e], d = dst[e];
    int pos = atomicAdd(&cursor[d], 1);
    csr_src[pos] = s;
    csr_w[pos]   = dis[s] * dis[d];
}

// ---------------- per-node aggregation: out[n] = sum_{e->n} w_e * hin[src_e] + dis[n]^2 * hin[n]
// one 64-lane wave per node; F/64 floats per lane, vectorized loads
template<int F>
__global__ __launch_bounds__(256) void agg_kernel(
    const float* __restrict__ hin, const int* __restrict__ row_start,
    const int* __restrict__ csr_src, const float* __restrict__ csr_w,
    const float* __restrict__ dis, float* __restrict__ out)
{
    constexpr int VEC = F / 64;
    using VT = typename VecPick<VEC>::T;
    const int lane = threadIdx.x & 63;
    const int node = blockIdx.x * 4 + (threadIdx.x >> 6);
    if (node >= N_NODES) return;

    float acc[VEC];
    {
        const float dn = dis[node];
        const float sw = dn * dn;
        VT sv = *reinterpret_cast<const VT*>(hin + (size_t)node * F + lane * VEC);
        const float* sf = reinterpret_cast<const float*>(&sv);
        #pragma unroll
        for (int v = 0; v < VEC; ++v) acc[v] = sf[v] * sw;
    }

    int j = row_start[node];
    const int end = row_start[node + 1];
    for (; j + 1 < end; j += 2) {
        int   s0 = csr_src[j],  s1 = csr_src[j + 1];
        float w0 = csr_w[j],    w1 = csr_w[j + 1];
        VT t0 = *reinterpret_cast<const VT*>(hin + (size_t)s0 * F + lane * VEC);
        VT t1 = *reinterpret_cast<const VT*>(hin + (size_t)s1 * F + lane * VEC);
        const float* f0 = reinterpret_cast<const float*>(&t0);
        const float* f1 = reinterpret_cast<const float*>(&t1);
        #pragma unroll
        for (int v = 0; v < VEC; ++v) acc[v] = fmaf(f0[v], w0, acc[v]);
        #pragma unroll
        for (int v = 0; v < VEC; ++v) acc[v] = fmaf(f1[v], w1, acc[v]);
    }
    if (j < end) {
        int   s0 = csr_src[j];
        float w0 = csr_w[j];
        VT t0 = *reinterpret_cast<const VT*>(hin + (size_t)s0 * F + lane * VEC);
        const float* f0 = reinterpret_cast<const float*>(&t0);
        #pragma unroll
        for (int v = 0; v < VEC; ++v) acc[v] = fmaf(f0[v], w0, acc[v]);
    }

    VT res;
    float* rf = reinterpret_cast<float*>(&res);
    #pragma unroll
    for (int v = 0; v < VEC; ++v) rf[v] = acc[v];
    *reinterpret_cast<VT*>(out + (size_t)node * F + lane * VEC) = res;
}

// ---------------- fp32 tiled GEMM: C[M,N] = A[M,K] @ W[K,N] + bias, optional ReLU
// BM=BN=64, BK=32, 256 threads, 4x4 microtile per thread. A rows padded to NPAD (no load guards).
__global__ __launch_bounds__(256) void gemm_kernel(
    const float* __restrict__ A, const float* __restrict__ W,
    const float* __restrict__ bias, float* __restrict__ C,
    int M, int K, int Ncols, int relu)
{
    constexpr int BM = 64, BN = 64, BK = 32;
    __shared__ float As[BK][BM + 4];   // transposed A tile, +4 pad: aligned b128 reads, fewer write conflicts
    __shared__ float Bs[BK][BN + 4];
    const int tid = threadIdx.x;
    const int tx  = tid & 15;
    const int ty  = tid >> 4;
    const int row0 = blockIdx.x * BM;
    const int col0 = blockIdx.y * BN;
    float acc[4][4] = {};

    for (int k0 = 0; k0 < K; k0 += BK) {
        #pragma unroll
        for (int pass = 0; pass < 2; ++pass) {
            {   // A: 64 rows x 32 k, transposed into As[k][m]
                int ar = (tid >> 3) + pass * 32;
                int ak = (tid & 7) * 4;
                float4 av = *reinterpret_cast<const float4*>(A + (size_t)(row0 + ar) * K + (k0 + ak));
                As[ak + 0][ar] = av.x; As[ak + 1][ar] = av.y;
                As[ak + 2][ar] = av.z; As[ak + 3][ar] = av.w;
            }
            {   // B: 32 k x 64 n
                int bk = (tid >> 4) + pass * 16;
                int bn = (tid & 15) * 4;
                *reinterpret_cast<float4*>(&Bs[bk][bn]) =
                    *reinterpret_cast<const float4*>(W + (size_t)(k0 + bk) * Ncols + (col0 + bn));
            }
        }
        __syncthreads();
        #pragma unroll
        for (int k = 0; k < BK; ++k) {
            float4 a4 = *reinterpret_cast<const float4*>(&As[k][ty * 4]);
            float4 b4 = *reinterpret_cast<const float4*>(&Bs[k][tx * 4]);
            float av[4] = {a4.x, a4.y, a4.z, a4.w};
            float bv[4] = {b4.x, b4.y, b4.z, b4.w};
            #pragma unroll
            for (int i = 0; i < 4; ++i)
                #pragma unroll
                for (int j = 0; j < 4; ++j)
                    acc[i][j] = fmaf(av[i], bv[j], acc[i][j]);
        }
        __syncthreads();
    }

    #pragma unroll
    for (int i = 0; i < 4; ++i) {
        int r = row0 + ty * 4 + i;
        if (r < M) {
            int c = col0 + tx * 4;
            float4 v;
            v.x = acc[i][0] + bias[c + 0];
            v.y = acc[i][1] + bias[c + 1];
            v.z = acc[i][2] + bias[c + 2];
            v.w = acc[i][3] + bias[c + 3];
            if (relu) {
                v.x = fmaxf(v.x, 0.f); v.y = fmaxf(v.y, 0.f);
                v.z = fmaxf(v.z, 0.f); v.w = fmaxf(v.w, 0.f);
            }
            *reinterpret_cast<float4*>(C + (size_t)r * Ncols + c) = v;
        }
    }
}

// ---------------- graph segment boundaries (batch is sorted) ----------------
__global__ void gstart_kernel(const int* __restrict__ batch, int* __restrict__ gstart) {
    int g = blockIdx.x * blockDim.x + threadIdx.x;
    if (g > N_GRAPHS) return;
    int lo = 0, hi = N_NODES;            // first i with batch[i] >= g
    while (lo < hi) {
        int mid = (lo + hi) >> 1;
        if (batch[mid] < g) lo = mid + 1; else hi = mid;
    }
    gstart[g] = lo;
}

// one block per graph; thread t owns feature t
__global__ __launch_bounds__(256) void pool_kernel(const float* __restrict__ h,
                                                   const int* __restrict__ gstart,
                                                   float* __restrict__ pooled) {
    int g = blockIdx.x, t = threadIdx.x;
    int s = gstart[g], e = gstart[g + 1];
    float acc = 0.f;
    for (int n = s; n < e; ++n) acc += h[(size_t)n * HID + t];
    float cnt = (float)(e - s);
    pooled[g * HID + t] = acc / fmaxf(cnt, 1.0f);
}

// fused MLP head: out[g] = relu(pooled @ Wm1 + bm1) @ Wm2 + bm2
__global__ __launch_bounds__(256) void mlp_kernel(const float* __restrict__ pooled,
                                                  const float* __restrict__ Wm1,
                                                  const float* __restrict__ bm1,
                                                  const float* __restrict__ Wm2,
                                                  const float* __restrict__ bm2,
                                                  float* __restrict__ out) {
    __shared__ float p[HID];
    __shared__ float red[HID];
    int g = blockIdx.x, t = threadIdx.x;
    p[t] = pooled[g * HID + t];
    __syncthreads();
    float acc = bm1[t];
    for (int k = 0; k < HID; ++k) acc = fmaf(p[k], Wm1[k * HID + t], acc);
    float hval = fmaxf(acc, 0.f);
    red[t] = hval * Wm2[t];
    __syncthreads();
    for (int s = 128; s > 0; s >>= 1) {
        if (t < s) red[t] += red[t + s];
        __syncthreads();
    }
    if (t == 0) out[g] = red[0] + bm2[0];
}

// ---------------- launch ----------------
extern "C" void kernel_launch(void* const* d_in, const int* in_sizes, int n_in,
                              void* d_out, int out_size, void* d_ws, size_t ws_size,
                              hipStream_t stream) {
    const float* x    = (const float*)d_in[0];
    const int*   ei   = (const int*)d_in[1];
    const int*   batch= (const int*)d_in[2];
    const float* W0   = (const float*)d_in[3];
    const float* b0   = (const float*)d_in[4];
    const float* W1   = (const float*)d_in[5];
    const float* b1   = (const float*)d_in[6];
    const float* W2   = (const float*)d_in[7];
    const float* b2   = (const float*)d_in[8];
    const float* Wm1  = (const float*)d_in[9];
    const float* bm1  = (const float*)d_in[10];
    const float* Wm2  = (const float*)d_in[11];
    const float* bm2  = (const float*)d_in[12];
    float* out = (float*)d_out;

    char* ws = (char*)d_ws;
    size_t off = 0;
    auto alloc = [&](size_t bytes) -> void* {
        void* p = ws + off;
        off += (bytes + 255) & ~(size_t)255;
        return p;
    };
    int*   deg       = (int*)  alloc((size_t)N_NODES * 4);
    float* dis       = (float*)alloc((size_t)N_NODES * 4);
    int*   row_start = (int*)  alloc((size_t)(N_NODES + 1) * 4);
    int*   cursor    = (int*)  alloc((size_t)N_NODES * 4);
    int*   csr_src   = (int*)  alloc((size_t)N_EDGES * 4);
    float* csr_w     = (float*)alloc((size_t)N_EDGES * 4);
    int*   gstart    = (int*)  alloc((size_t)(N_GRAPHS + 1) * 4);
    float* pooled    = (float*)alloc((size_t)N_GRAPHS * HID * 4);
    float* bufA      = (float*)alloc((size_t)NPAD * HID * 4);
    float* bufB      = (float*)alloc((size_t)NPAD * HID * 4);

    const int* src = ei;
    const int* dst = ei + N_EDGES;

    hipMemsetAsync(deg, 0, (size_t)N_NODES * 4, stream);
    deg_kernel <<<(N_EDGES + 255) / 256, 256, 0, stream>>>(dst, deg);
    dis_kernel <<<(N_NODES + 255) / 256, 256, 0, stream>>>(deg, dis);
    scan_kernel<<<1, 1024, 0, stream>>>(deg, row_start, cursor, N_NODES);
    fill_csr   <<<(N_EDGES + 255) / 256, 256, 0, stream>>>(src, dst, dis, cursor, csr_src, csr_w);

    dim3 ggrid(NPAD / 64, HID / 64);

    // layer 0: aggregate x (128-dim) first, then GEMM  ( (A_hat x) W0 )
    agg_kernel<F_IN><<<(N_NODES + 3) / 4, 256, 0, stream>>>(x, row_start, csr_src, csr_w, dis, bufA);
    gemm_kernel<<<ggrid, 256, 0, stream>>>(bufA, W0, b0, bufB, N_NODES, F_IN, HID, 1);

    // layer 1
    agg_kernel<HID><<<(N_NODES + 3) / 4, 256, 0, stream>>>(bufB, row_start, csr_src, csr_w, dis, bufA);
    gemm_kernel<<<ggrid, 256, 0, stream>>>(bufA, W1, b1, bufB, N_NODES, HID, HID, 1);

    // layer 2
    agg_kernel<HID><<<(N_NODES + 3) / 4, 256, 0, stream>>>(bufB, row_start, csr_src, csr_w, dis, bufA);
    gemm_kernel<<<ggrid, 256, 0, stream>>>(bufA, W2, b2, bufB, N_NODES, HID, HID, 1);

    // pool + MLP head
    gstart_kernel<<<3, 256, 0, stream>>>(batch, gstart);
    pool_kernel  <<<N_GRAPHS, HID, 0, stream>>>(bufB, gstart, pooled);
    mlp_kernel   <<<N_GRAPHS, HID, 0, stream>>>(pooled, Wm1, bm1, Wm2, bm2, out);
}

// Round 2
// 460.176 us; speedup vs baseline: 1.8354x; 1.8354x over previous
//
#include <hip/hip_runtime.h>

// ---------------- problem constants ----------------
constexpr int N_NODES  = 50000;
constexpr int N_EDGES  = 800000;
constexpr int N_GRAPHS = 512;
constexpr int F_IN     = 128;
constexpr int HID      = 256;
constexpr int NPAD     = 50048;   // 391*128, padded rows: GEMM tiles need no guards

typedef short short8 __attribute__((ext_vector_type(8)));
typedef float f32x4  __attribute__((ext_vector_type(4)));

// bf16 helpers (raw ushort storage; RNE rounding)
__device__ __forceinline__ unsigned short f2b(float f) {
    unsigned u = __float_as_uint(f);
    u += 0x7fffu + ((u >> 16) & 1u);
    return (unsigned short)(u >> 16);
}
__device__ __forceinline__ float b2f_lo(unsigned u) { return __uint_as_float(u << 16); }
__device__ __forceinline__ float b2f_hi(unsigned u) { return __uint_as_float(u & 0xffff0000u); }

// ---------------- degree histogram ----------------
__global__ void deg_kernel(const int* __restrict__ dst, int* __restrict__ deg) {
    int e = blockIdx.x * blockDim.x + threadIdx.x;
    if (e >= N_EDGES) return;
    atomicAdd(&deg[dst[e]], 1);
}

__global__ void dis_kernel(const int* __restrict__ deg, float* __restrict__ dis) {
    int i = blockIdx.x * blockDim.x + threadIdx.x;
    if (i >= N_NODES) return;
    dis[i] = rsqrtf((float)deg[i] + 1.0f);
}

// ---------------- parallel scan (3 kernels, 1024 elems/block) ----------------
__global__ void block_sum_kernel(const int* __restrict__ deg, int* __restrict__ bsum, int n) {
    __shared__ int sm[256];
    int t = threadIdx.x, base = blockIdx.x * 1024;
    int s = 0;
    #pragma unroll
    for (int i = 0; i < 4; ++i) { int idx = base + t + i * 256; if (idx < n) s += deg[idx]; }
    sm[t] = s; __syncthreads();
    for (int o = 128; o > 0; o >>= 1) { if (t < o) sm[t] += sm[t + o]; __syncthreads(); }
    if (t == 0) bsum[blockIdx.x] = sm[0];
}

__global__ void scan_bsum_kernel(int* __restrict__ bsum, int nb) {   // 1 block, 64 threads
    __shared__ int sm[64];
    int t = threadIdx.x;
    int v = (t < nb) ? bsum[t] : 0;
    sm[t] = v; __syncthreads();
    for (int o = 1; o < 64; o <<= 1) {
        int a = (t >= o) ? sm[t - o] : 0; __syncthreads();
        sm[t] += a; __syncthreads();
    }
    if (t < nb) bsum[t] = sm[t] - v;   // exclusive
}

__global__ void scan_local_kernel(const int* __restrict__ deg, const int* __restrict__ bsum,
                                  int* __restrict__ row_start, int* __restrict__ cursor, int n) {
    __shared__ int sm[256];
    int t = threadIdx.x, base = blockIdx.x * 1024;
    int idx0 = base + t * 4;
    int v[4], s = 0;
    #pragma unroll
    for (int i = 0; i < 4; ++i) { int id = idx0 + i; v[i] = (id < n) ? deg[id] : 0; s += v[i]; }
    sm[t] = s; __syncthreads();
    for (int o = 1; o < 256; o <<= 1) {
        int a = (t >= o) ? sm[t - o] : 0; __syncthreads();
        sm[t] += a; __syncthreads();
    }
    int excl = bsum[blockIdx.x] + sm[t] - s;
    #pragma unroll
    for (int i = 0; i < 4; ++i) {
        int id = idx0 + i;
        if (id < n) { row_start[id] = excl; cursor[id] = excl; }
        excl += v[i];
    }
    if (blockIdx.x == gridDim.x - 1 && t == 255) row_start[n] = excl;  // == N_EDGES
}

// ---------------- CSR scatter: entry = (src, w_bits) interleaved ----------------
__global__ void fill_csr(const int* __restrict__ src, const int* __restrict__ dst,
                         const float* __restrict__ dis, int* __restrict__ cursor,
                         int2* __restrict__ csr) {
    int e = blockIdx.x * blockDim.x + threadIdx.x;
    if (e >= N_EDGES) return;
    int s = src[e], d = dst[e];
    int pos = atomicAdd(&cursor[d], 1);
    float w = dis[s] * dis[d];
    csr[pos] = make_int2(s, __float_as_int(w));
}

// ---------------- fp32 -> bf16 convert (x) ----------------
__global__ void conv_bf16_kernel(const float* __restrict__ in, unsigned short* __restrict__ out, int n4) {
    int i = blockIdx.x * blockDim.x + threadIdx.x;
    if (i >= n4) return;
    float4 v = *reinterpret_cast<const float4*>(in + (size_t)i * 4);
    unsigned r0 = (unsigned)f2b(v.x) | ((unsigned)f2b(v.y) << 16);
    unsigned r1 = (unsigned)f2b(v.z) | ((unsigned)f2b(v.w) << 16);
    uint2 r = make_uint2(r0, r1);
    *reinterpret_cast<uint2*>(out + (size_t)i * 4) = r;
}

// ---------------- weight transpose+convert: Wt[n][k] = bf16(W[k][n]), N=256 ----------------
__global__ void wt_kernel(const float* __restrict__ W, unsigned short* __restrict__ Wt, int K) {
    int i = blockIdx.x * blockDim.x + threadIdx.x;
    if (i >= K * 256) return;
    int k = i >> 8, n = i & 255;
    Wt[n * K + k] = f2b(W[i]);
}

// ---------------- aggregation, bf16 in / bf16 out, fp32 accumulate ----------------
// one 64-lane wave per node; UV = uints(2xbf16) per lane: 1 (F=128) or 2 (F=256)
template<int F>
__global__ __launch_bounds__(256) void agg_bf16(
    const unsigned short* __restrict__ hin, const int* __restrict__ row_start,
    const int2* __restrict__ csr, const float* __restrict__ dis,
    unsigned short* __restrict__ out)
{
    constexpr int UV = F / 128;
    const int lane = threadIdx.x & 63;
    const int node = blockIdx.x * 4 + (threadIdx.x >> 6);
    if (node >= N_NODES) return;

    float a0 = 0.f, a1 = 0.f, a2 = 0.f, a3 = 0.f;
    {
        float dn = dis[node], sw = dn * dn;
        if constexpr (UV == 1) {
            unsigned u = *reinterpret_cast<const unsigned*>(hin + (size_t)node * F + lane * 2);
            a0 = b2f_lo(u) * sw; a1 = b2f_hi(u) * sw;
        } else {
            uint2 u = *reinterpret_cast<const uint2*>(hin + (size_t)node * F + lane * 4);
            a0 = b2f_lo(u.x) * sw; a1 = b2f_hi(u.x) * sw;
            a2 = b2f_lo(u.y) * sw; a3 = b2f_hi(u.y) * sw;
        }
    }

    int j = row_start[node];
    const int end = row_start[node + 1];
    for (; j + 3 < end; j += 4) {
        int2 c0 = csr[j], c1 = csr[j + 1], c2 = csr[j + 2], c3 = csr[j + 3];
        if constexpr (UV == 1) {
            unsigned u0 = *reinterpret_cast<const unsigned*>(hin + (size_t)c0.x * F + lane * 2);
            unsigned u1 = *reinterpret_cast<const unsigned*>(hin + (size_t)c1.x * F + lane * 2);
            unsigned u2 = *reinterpret_cast<const unsigned*>(hin + (size_t)c2.x * F + lane * 2);
            unsigned u3 = *reinterpret_cast<const unsigned*>(hin + (size_t)c3.x * F + lane * 2);
            float w0 = __int_as_float(c0.y), w1 = __int_as_float(c1.y);
            float w2 = __int_as_float(c2.y), w3 = __int_as_float(c3.y);
            a0 = fmaf(b2f_lo(u0), w0, a0); a1 = fmaf(b2f_hi(u0), w0, a1);
            a0 = fmaf(b2f_lo(u1), w1, a0); a1 = fmaf(b2f_hi(u1), w1, a1);
            a0 = fmaf(b2f_lo(u2), w2, a0); a1 = fmaf(b2f_hi(u2), w2, a1);
            a0 = fmaf(b2f_lo(u3), w3, a0); a1 = fmaf(b2f_hi(u3), w3, a1);
        } else {
            uint2 u0 = *reinterpret_cast<const uint2*>(hin + (size_t)c0.x * F + lane * 4);
            uint2 u1 = *reinterpret_cast<const uint2*>(hin + (size_t)c1.x * F + lane * 4);
            uint2 u2 = *reinterpret_cast<const uint2*>(hin + (size_t)c2.x * F + lane * 4);
            uint2 u3 = *reinterpret_cast<const uint2*>(hin + (size_t)c3.x * F + lane * 4);
            float w0 = __int_as_float(c0.y), w1 = __int_as_float(c1.y);
            float w2 = __int_as_float(c2.y), w3 = __int_as_float(c3.y);
            a0 = fmaf(b2f_lo(u0.x), w0, a0); a1 = fmaf(b2f_hi(u0.x), w0, a1);
            a2 = fmaf(b2f_lo(u0.y), w0, a2); a3 = fmaf(b2f_hi(u0.y), w0, a3);
            a0 = fmaf(b2f_lo(u1.x), w1, a0); a1 = fmaf(b2f_hi(u1.x), w1, a1);
            a2 = fmaf(b2f_lo(u1.y), w1, a2); a3 = fmaf(b2f_hi(u1.y), w1, a3);
            a0 = fmaf(b2f_lo(u2.x), w2, a0); a1 = fmaf(b2f_hi(u2.x), w2, a1);
            a2 = fmaf(b2f_lo(u2.y), w2, a2); a3 = fmaf(b2f_hi(u2.y), w2, a3);
            a0 = fmaf(b2f_lo(u3.x), w3, a0); a1 = fmaf(b2f_hi(u3.x), w3, a1);
            a2 = fmaf(b2f_lo(u3.y), w3, a2); a3 = fmaf(b2f_hi(u3.y), w3, a3);
        }
    }
    for (; j < end; ++j) {
        int2 c0 = csr[j];
        float w0 = __int_as_float(c0.y);
        if constexpr (UV == 1) {
            unsigned u0 = *reinterpret_cast<const unsigned*>(hin + (size_t)c0.x * F + lane * 2);
            a0 = fmaf(b2f_lo(u0), w0, a0); a1 = fmaf(b2f_hi(u0), w0, a1);
        } else {
            uint2 u0 = *reinterpret_cast<const uint2*>(hin + (size_t)c0.x * F + lane * 4);
            a0 = fmaf(b2f_lo(u0.x), w0, a0); a1 = fmaf(b2f_hi(u0.x), w0, a1);
            a2 = fmaf(b2f_lo(u0.y), w0, a2); a3 = fmaf(b2f_hi(u0.y), w0, a3);
        }
    }

    if constexpr (UV == 1) {
        unsigned r = (unsigned)f2b(a0) | ((unsigned)f2b(a1) << 16);
        *reinterpret_cast<unsigned*>(out + (size_t)node * F + lane * 2) = r;
    } else {
        uint2 r;
        r.x = (unsigned)f2b(a0) | ((unsigned)f2b(a1) << 16);
        r.y = (unsigned)f2b(a2) | ((unsigned)f2b(a3) << 16);
        *reinterpret_cast<uint2*>(out + (size_t)node * F + lane * 4) = r;
    }
}

// ---------------- bf16 MFMA GEMM: C[NPAD,256] = A[NPAD,K] @ Bt[256,K]^T + bias (ReLU) ----------------
// 128x128 tile, 256 threads = 4 waves in 2x2, each wave 64x64 via 4x4 grid of 16x16x32 MFMA.
// LDS in fragment order: As[kgrp(4)][row(128)][8 bf16] -> contiguous 16B frag reads.
__global__ __launch_bounds__(256) void gemm_mfma(
    const unsigned short* __restrict__ A,
    const unsigned short* __restrict__ Bt,
    const float* __restrict__ bias,
    unsigned short* __restrict__ C,
    int K, int relu)
{
    __shared__ __align__(16) unsigned short As[4 * 128 * 8];
    __shared__ __align__(16) unsigned short Bs[4 * 128 * 8];
    const int t    = threadIdx.x;
    const int lane = t & 63;
    const int w    = t >> 6;
    const int wm   = w & 1, wn = w >> 1;
    const int q    = lane >> 4, m = lane & 15;
    const int row0 = blockIdx.x * 128;
    const int col0 = blockIdx.y * 128;
    const int r_   = t >> 2, c_ = t & 3;

    f32x4 acc[4][4] = {};

    for (int k0 = 0; k0 < K; k0 += 32) {
        #pragma unroll
        for (int pass = 0; pass < 2; ++pass) {
            int r = r_ + pass * 64;
            uint4 av = *reinterpret_cast<const uint4*>(A  + (size_t)(row0 + r) * K + k0 + c_ * 8);
            uint4 bv = *reinterpret_cast<const uint4*>(Bt + (size_t)(col0 + r) * K + k0 + c_ * 8);
            *reinterpret_cast<uint4*>(&As[(c_ * 128 + r) * 8]) = av;
            *reinterpret_cast<uint4*>(&Bs[(c_ * 128 + r) * 8]) = bv;
        }
        __syncthreads();
        short8 af[4], bf[4];
        #pragma unroll
        for (int i = 0; i < 4; ++i)
            af[i] = *reinterpret_cast<const short8*>(&As[(q * 128 + wm * 64 + i * 16 + m) * 8]);
        #pragma unroll
        for (int j = 0; j < 4; ++j)
            bf[j] = *reinterpret_cast<const short8*>(&Bs[(q * 128 + wn * 64 + j * 16 + m) * 8]);
        #pragma unroll
        for (int i = 0; i < 4; ++i)
            #pragma unroll
            for (int j = 0; j < 4; ++j)
                acc[i][j] = __builtin_amdgcn_mfma_f32_16x16x32_bf16(af[i], bf[j], acc[i][j], 0, 0, 0);
        __syncthreads();
    }

    // epilogue: C/D layout col = lane&15, row = (lane>>4)*4 + reg
    #pragma unroll
    for (int j = 0; j < 4; ++j) {
        int col = col0 + wn * 64 + j * 16 + m;
        float bj = bias[col];
        #pragma unroll
        for (int i = 0; i < 4; ++i) {
            int rowb = row0 + wm * 64 + i * 16 + q * 4;
            #pragma unroll
            for (int r = 0; r < 4; ++r) {
                float v = acc[i][j][r] + bj;
                if (relu) v = fmaxf(v, 0.f);
                C[(size_t)(rowb + r) * 256 + col] = f2b(v);
            }
        }
    }
}

// ---------------- graph boundaries (batch sorted) ----------------
__global__ void gstart_kernel(const int* __restrict__ batch, int* __restrict__ gstart) {
    int g = blockIdx.x * blockDim.x + threadIdx.x;
    if (g > N_GRAPHS) return;
    int lo = 0, hi = N_NODES;
    while (lo < hi) {
        int mid = (lo + hi) >> 1;
        if (batch[mid] < g) lo = mid + 1; else hi = mid;
    }
    gstart[g] = lo;
}

__global__ __launch_bounds__(256) void pool_kernel(const unsigned short* __restrict__ h,
                                                   const int* __restrict__ gstart,
                                                   float* __restrict__ pooled) {
    int g = blockIdx.x, t = threadIdx.x;
    int s = gstart[g], e = gstart[g + 1];
    float acc = 0.f;
    for (int n = s; n < e; ++n) acc += b2f_lo((unsigned)h[(size_t)n * HID + t]);
    float cnt = (float)(e - s);
    pooled[g * HID + t] = acc / fmaxf(cnt, 1.0f);
}

__global__ __launch_bounds__(256) void mlp_kernel(const float* __restrict__ pooled,
                                                  const float* __restrict__ Wm1,
                                                  const float* __restrict__ bm1,
                                                  const float* __restrict__ Wm2,
                                                  const float* __restrict__ bm2,
                                                  float* __restrict__ out) {
    __shared__ float p[HID];
    __shared__ float red[HID];
    int g = blockIdx.x, t = threadIdx.x;
    p[t] = pooled[g * HID + t];
    __syncthreads();
    float acc = bm1[t];
    for (int k = 0; k < HID; ++k) acc = fmaf(p[k], Wm1[k * HID + t], acc);
    float hval = fmaxf(acc, 0.f);
    red[t] = hval * Wm2[t];
    __syncthreads();
    for (int s = 128; s > 0; s >>= 1) {
        if (t < s) red[t] += red[t + s];
        __syncthreads();
    }
    if (t == 0) out[g] = red[0] + bm2[0];
}

// ---------------- launch ----------------
extern "C" void kernel_launch(void* const* d_in, const int* in_sizes, int n_in,
                              void* d_out, int out_size, void* d_ws, size_t ws_size,
                              hipStream_t stream) {
    const float* x    = (const float*)d_in[0];
    const int*   ei   = (const int*)d_in[1];
    const int*   batch= (const int*)d_in[2];
    const float* W0   = (const float*)d_in[3];
    const float* b0   = (const float*)d_in[4];
    const float* W1   = (const float*)d_in[5];
    const float* b1   = (const float*)d_in[6];
    const float* W2   = (const float*)d_in[7];
    const float* b2   = (const float*)d_in[8];
    const float* Wm1  = (const float*)d_in[9];
    const float* bm1  = (const float*)d_in[10];
    const float* Wm2  = (const float*)d_in[11];
    const float* bm2  = (const float*)d_in[12];
    float* out = (float*)d_out;

    char* ws = (char*)d_ws;
    size_t off = 0;
    auto alloc = [&](size_t bytes) -> void* {
        void* p = ws + off;
        off += (bytes + 255) & ~(size_t)255;
        return p;
    };
    int*   deg       = (int*)  alloc((size_t)N_NODES * 4);
    float* dis       = (float*)alloc((size_t)N_NODES * 4);
    int*   row_start = (int*)  alloc((size_t)(N_NODES + 1) * 4);
    int*   cursor    = (int*)  alloc((size_t)N_NODES * 4);
    int*   bsum      = (int*)  alloc((size_t)64 * 4);
    int2*  csr       = (int2*) alloc((size_t)N_EDGES * 8);
    int*   gstart    = (int*)  alloc((size_t)(N_GRAPHS + 1) * 4);
    float* pooled    = (float*)alloc((size_t)N_GRAPHS * HID * 4);
    unsigned short* x_bf = (unsigned short*)alloc((size_t)N_NODES * F_IN * 2);
    unsigned short* Wt0  = (unsigned short*)alloc((size_t)F_IN * HID * 2);
    unsigned short* Wt1  = (unsigned short*)alloc((size_t)HID * HID * 2);
    unsigned short* Wt2  = (unsigned short*)alloc((size_t)HID * HID * 2);
    unsigned short* bufA = (unsigned short*)alloc((size_t)NPAD * HID * 2);
    unsigned short* bufB = (unsigned short*)alloc((size_t)NPAD * HID * 2);

    const int* src = ei;
    const int* dst = ei + N_EDGES;
    const int NB = (N_NODES + 1023) / 1024;   // 49

    hipMemsetAsync(deg, 0, (size_t)N_NODES * 4, stream);
    deg_kernel      <<<(N_EDGES + 255) / 256, 256, 0, stream>>>(dst, deg);
    dis_kernel      <<<(N_NODES + 255) / 256, 256, 0, stream>>>(deg, dis);
    block_sum_kernel<<<NB, 256, 0, stream>>>(deg, bsum, N_NODES);
    scan_bsum_kernel<<<1, 64, 0, stream>>>(bsum, NB);
    scan_local_kernel<<<NB, 256, 0, stream>>>(deg, bsum, row_start, cursor, N_NODES);
    fill_csr        <<<(N_EDGES + 255) / 256, 256, 0, stream>>>(src, dst, dis, cursor, csr);

    conv_bf16_kernel<<<(N_NODES * F_IN / 4 + 255) / 256, 256, 0, stream>>>(x, x_bf, N_NODES * F_IN / 4);
    wt_kernel<<<(F_IN * HID + 255) / 256, 256, 0, stream>>>(W0, Wt0, F_IN);
    wt_kernel<<<(HID * HID + 255) / 256, 256, 0, stream>>>(W1, Wt1, HID);
    wt_kernel<<<(HID * HID + 255) / 256, 256, 0, stream>>>(W2, Wt2, HID);

    dim3 ggrid(NPAD / 128, 2);

    // layer 0: aggregate x (bf16, 128-dim) first, then MFMA GEMM
    agg_bf16<F_IN><<<(N_NODES + 3) / 4, 256, 0, stream>>>(x_bf, row_start, csr, dis, bufA);
    gemm_mfma<<<ggrid, 256, 0, stream>>>(bufA, Wt0, b0, bufB, F_IN, 1);

    // layer 1
    agg_bf16<HID><<<(N_NODES + 3) / 4, 256, 0, stream>>>(bufB, row_start, csr, dis, bufA);
    gemm_mfma<<<ggrid, 256, 0, stream>>>(bufA, Wt1, b1, bufB, HID, 1);

    // layer 2
    agg_bf16<HID><<<(N_NODES + 3) / 4, 256, 0, stream>>>(bufB, row_start, csr, dis, bufA);
    gemm_mfma<<<ggrid, 256, 0, stream>>>(bufA, Wt2, b2, bufB, HID, 1);

    // pool + MLP head (fp32)
    gstart_kernel<<<3, 256, 0, stream>>>(batch, gstart);
    pool_kernel  <<<N_GRAPHS, HID, 0, stream>>>(bufB, gstart, pooled);
    mlp_kernel   <<<N_GRAPHS, HID, 0, stream>>>(pooled, Wm1, bm1, Wm2, bm2, out);
}

// Round 3
// 435.834 us; speedup vs baseline: 1.9379x; 1.0559x over previous
//
#include <hip/hip_runtime.h>

// ---------------- problem constants ----------------
constexpr int N_NODES  = 50000;
constexpr int N_EDGES  = 800000;
constexpr int N_GRAPHS = 512;
constexpr int F_IN     = 128;
constexpr int HID      = 256;
constexpr int NPAD     = 50048;   // 391*128 padded rows: GEMM tiles need no guards

typedef short short8 __attribute__((ext_vector_type(8)));
typedef float f32x4  __attribute__((ext_vector_type(4)));

// bf16 helpers (raw ushort storage; RNE rounding)
__device__ __forceinline__ unsigned short f2b(float f) {
    unsigned u = __float_as_uint(f);
    u += 0x7fffu + ((u >> 16) & 1u);
    return (unsigned short)(u >> 16);
}
__device__ __forceinline__ float b2f_lo(unsigned u) { return __uint_as_float(u << 16); }
__device__ __forceinline__ float b2f_hi(unsigned u) { return __uint_as_float(u & 0xffff0000u); }

// ---------------- fused prep: deg histogram + x->bf16 + weight transpose ----------------
// blocks [0,3125): deg atomics over 800k edges
// blocks [3125,9375): x fp32 -> bf16 (1.6M float4)
// blocks [9375,10015): W0/W1/W2 transpose+convert (163840 elems)
__global__ __launch_bounds__(256) void prep_kernel(
    const int* __restrict__ dst, int* __restrict__ deg,
    const float* __restrict__ x, unsigned short* __restrict__ x_bf,
    const float* __restrict__ W0, const float* __restrict__ W1, const float* __restrict__ W2,
    unsigned short* __restrict__ Wt0, unsigned short* __restrict__ Wt1, unsigned short* __restrict__ Wt2)
{
    const int b = blockIdx.x, t = threadIdx.x;
    if (b < 3125) {
        int e = b * 256 + t;                       // 3125*256 == 800000 exactly
        atomicAdd(&deg[dst[e]], 1);
    } else if (b < 9375) {
        int i = (b - 3125) * 256 + t;              // 6250*256 == 1.6M exactly
        float4 v = *reinterpret_cast<const float4*>(x + (size_t)i * 4);
        unsigned r0 = (unsigned)f2b(v.x) | ((unsigned)f2b(v.y) << 16);
        unsigned r1 = (unsigned)f2b(v.z) | ((unsigned)f2b(v.w) << 16);
        *reinterpret_cast<uint2*>(x_bf + (size_t)i * 4) = make_uint2(r0, r1);
    } else {
        int i = (b - 9375) * 256 + t;              // 640*256 == 163840 exactly
        if (i < 32768)        { int k = i >> 8, n = i & 255;               Wt0[n * 128 + k] = f2b(W0[i]); }
        else if (i < 98304)   { int j = i - 32768; int k = j >> 8, n = j & 255; Wt1[n * 256 + k] = f2b(W1[j]); }
        else                  { int j = i - 98304; int k = j >> 8, n = j & 255; Wt2[n * 256 + k] = f2b(W2[j]); }
    }
}

// ---------------- parallel scan (3 kernels, 1024 elems/block) + dis fused ----------------
__global__ void block_sum_dis_kernel(const int* __restrict__ deg, int* __restrict__ bsum,
                                     float* __restrict__ dis, int n) {
    __shared__ int sm[256];
    int t = threadIdx.x, base = blockIdx.x * 1024;
    int s = 0;
    #pragma unroll
    for (int i = 0; i < 4; ++i) {
        int idx = base + t + i * 256;
        if (idx < n) { int d = deg[idx]; s += d; dis[idx] = rsqrtf((float)d + 1.0f); }
    }
    sm[t] = s; __syncthreads();
    for (int o = 128; o > 0; o >>= 1) { if (t < o) sm[t] += sm[t + o]; __syncthreads(); }
    if (t == 0) bsum[blockIdx.x] = sm[0];
}

__global__ void scan_bsum_kernel(int* __restrict__ bsum, int nb) {   // 1 block, 64 threads
    __shared__ int sm[64];
    int t = threadIdx.x;
    int v = (t < nb) ? bsum[t] : 0;
    sm[t] = v; __syncthreads();
    for (int o = 1; o < 64; o <<= 1) {
        int a = (t >= o) ? sm[t - o] : 0; __syncthreads();
        sm[t] += a; __syncthreads();
    }
    if (t < nb) bsum[t] = sm[t] - v;   // exclusive
}

__global__ void scan_local_kernel(const int* __restrict__ deg, const int* __restrict__ bsum,
                                  int* __restrict__ row_start, int* __restrict__ cursor, int n) {
    __shared__ int sm[256];
    int t = threadIdx.x, base = blockIdx.x * 1024;
    int idx0 = base + t * 4;
    int v[4], s = 0;
    #pragma unroll
    for (int i = 0; i < 4; ++i) { int id = idx0 + i; v[i] = (id < n) ? deg[id] : 0; s += v[i]; }
    sm[t] = s; __syncthreads();
    for (int o = 1; o < 256; o <<= 1) {
        int a = (t >= o) ? sm[t - o] : 0; __syncthreads();
        sm[t] += a; __syncthreads();
    }
    int excl = bsum[blockIdx.x] + sm[t] - s;
    #pragma unroll
    for (int i = 0; i < 4; ++i) {
        int id = idx0 + i;
        if (id < n) { row_start[id] = excl; cursor[id] = excl; }
        excl += v[i];
    }
    if (blockIdx.x == gridDim.x - 1 && t == 255) row_start[n] = excl;  // == N_EDGES
}

// ---------------- CSR scatter: entry = (src, w_bits) interleaved ----------------
__global__ void fill_csr(const int* __restrict__ src, const int* __restrict__ dst,
                         const float* __restrict__ dis, int* __restrict__ cursor,
                         int2* __restrict__ csr) {
    int e = blockIdx.x * blockDim.x + threadIdx.x;
    if (e >= N_EDGES) return;
    int s = src[e], d = dst[e];
    int pos = atomicAdd(&cursor[d], 1);
    float w = dis[s] * dis[d];
    csr[pos] = make_int2(s, __float_as_int(w));
}

// ---------------- aggregation, bf16 in/out, fp32 accumulate ----------------
// One 64-lane wave per node, split into NSUB row-subgroups of LPR=F/8 lanes.
// Each subgroup gathers a DIFFERENT edge with 16B/lane dwordx4 loads ->
// NSUB*4 outstanding gathers per wave. Partials combined via shfl_xor.
template<int F>
__global__ __launch_bounds__(256) void agg_bf16(
    const unsigned short* __restrict__ hin, const int* __restrict__ row_start,
    const int2* __restrict__ csr, const float* __restrict__ dis,
    unsigned short* __restrict__ out)
{
    constexpr int LPR  = F / 8;     // lanes per row: 32 (F=256) / 16 (F=128)
    constexpr int NSUB = 64 / LPR;  // subgroups per wave: 2 / 4
    const int lane = threadIdx.x & 63;
    const int sub  = lane / LPR;
    const int fc   = lane % LPR;    // 16-byte feature chunk index
    const int node = blockIdx.x * 4 + (threadIdx.x >> 6);
    if (node >= N_NODES) return;

    float acc[8];
    {   // self-loop term (only sub 0 contributes; all lanes issue the same cached load)
        float dn = dis[node];
        float sw = (sub == 0) ? dn * dn : 0.0f;
        uint2 u2[2];
        *reinterpret_cast<uint4*>(u2) =
            *reinterpret_cast<const uint4*>(hin + (size_t)node * F + fc * 8);
        #pragma unroll
        for (int h = 0; h < 2; ++h) {
            acc[h * 4 + 0] = b2f_lo(u2[h].x) * sw;
            acc[h * 4 + 1] = b2f_hi(u2[h].x) * sw;
            acc[h * 4 + 2] = b2f_lo(u2[h].y) * sw;
            acc[h * 4 + 3] = b2f_hi(u2[h].y) * sw;
        }
    }

    int j = row_start[node] + sub;
    const int end = row_start[node + 1];
    // unroll 4 per subgroup -> NSUB*4 edges in flight per wave
    for (; j + 3 * NSUB < end; j += 4 * NSUB) {
        int2 c[4];
        #pragma unroll
        for (int u = 0; u < 4; ++u) c[u] = csr[j + u * NSUB];
        #pragma unroll
        for (int u = 0; u < 4; ++u) {
            float w = __int_as_float(c[u].y);
            uint2 g[2];
            *reinterpret_cast<uint4*>(g) =
                *reinterpret_cast<const uint4*>(hin + (size_t)c[u].x * F + fc * 8);
            #pragma unroll
            for (int h = 0; h < 2; ++h) {
                acc[h * 4 + 0] = fmaf(b2f_lo(g[h].x), w, acc[h * 4 + 0]);
                acc[h * 4 + 1] = fmaf(b2f_hi(g[h].x), w, acc[h * 4 + 1]);
                acc[h * 4 + 2] = fmaf(b2f_lo(g[h].y), w, acc[h * 4 + 2]);
                acc[h * 4 + 3] = fmaf(b2f_hi(g[h].y), w, acc[h * 4 + 3]);
            }
        }
    }
    for (; j < end; j += NSUB) {
        int2 c0 = csr[j];
        float w = __int_as_float(c0.y);
        uint2 g[2];
        *reinterpret_cast<uint4*>(g) =
            *reinterpret_cast<const uint4*>(hin + (size_t)c0.x * F + fc * 8);
        #pragma unroll
        for (int h = 0; h < 2; ++h) {
            acc[h * 4 + 0] = fmaf(b2f_lo(g[h].x), w, acc[h * 4 + 0]);
            acc[h * 4 + 1] = fmaf(b2f_hi(g[h].x), w, acc[h * 4 + 1]);
            acc[h * 4 + 2] = fmaf(b2f_lo(g[h].y), w, acc[h * 4 + 2]);
            acc[h * 4 + 3] = fmaf(b2f_hi(g[h].y), w, acc[h * 4 + 3]);
        }
    }

    // combine subgroup partials (butterfly over the row-subgroup axis)
    #pragma unroll
    for (int k = 0; k < 8; ++k) {
        #pragma unroll
        for (int off = LPR; off < 64; off <<= 1)
            acc[k] += __shfl_xor(acc[k], off, 64);
    }

    if (sub == 0) {
        uint2 r[2];
        #pragma unroll
        for (int h = 0; h < 2; ++h) {
            r[h].x = (unsigned)f2b(acc[h * 4 + 0]) | ((unsigned)f2b(acc[h * 4 + 1]) << 16);
            r[h].y = (unsigned)f2b(acc[h * 4 + 2]) | ((unsigned)f2b(acc[h * 4 + 3]) << 16);
        }
        *reinterpret_cast<uint4*>(out + (size_t)node * F + fc * 8) =
            *reinterpret_cast<uint4*>(r);
    }
}

// ---------------- bf16 MFMA GEMM: C[NPAD,256] = A[NPAD,K] @ Bt[256,K]^T + bias (ReLU) ----------------
// 128x128 tile, 4 waves 2x2, each wave 64x64 via 4x4 of 16x16x32 MFMA.
// K templated + fully unrolled, double-buffered LDS -> 1 barrier per K-step.
template<int K>
__global__ __launch_bounds__(256) void gemm_mfma(
    const unsigned short* __restrict__ A,
    const unsigned short* __restrict__ Bt,
    const float* __restrict__ bias,
    unsigned short* __restrict__ C,
    int relu)
{
    __shared__ __align__(16) unsigned short As[2][4 * 128 * 8];
    __shared__ __align__(16) unsigned short Bs[2][4 * 128 * 8];
    const int t    = threadIdx.x;
    const int lane = t & 63;
    const int w    = t >> 6;
    const int wm   = w & 1, wn = w >> 1;
    const int q    = lane >> 4, m = lane & 15;
    const int row0 = blockIdx.x * 128;
    const int col0 = blockIdx.y * 128;
    const int r_   = t >> 2, c_ = t & 3;

    f32x4 acc[4][4] = {};

    auto stage = [&](int buf, int k0) {
        #pragma unroll
        for (int pass = 0; pass < 2; ++pass) {
            int r = r_ + pass * 64;
            uint4 av = *reinterpret_cast<const uint4*>(A  + (size_t)(row0 + r) * K + k0 + c_ * 8);
            uint4 bv = *reinterpret_cast<const uint4*>(Bt + (size_t)(col0 + r) * K + k0 + c_ * 8);
            *reinterpret_cast<uint4*>(&As[buf][(c_ * 128 + r) * 8]) = av;
            *reinterpret_cast<uint4*>(&Bs[buf][(c_ * 128 + r) * 8]) = bv;
        }
    };

    constexpr int NK = K / 32;
    stage(0, 0);
    __syncthreads();
    #pragma unroll
    for (int kb = 0; kb < NK; ++kb) {
        if (kb + 1 < NK) stage((kb + 1) & 1, (kb + 1) * 32);
        const unsigned short* as = As[kb & 1];
        const unsigned short* bs = Bs[kb & 1];
        short8 af[4], bf[4];
        #pragma unroll
        for (int i = 0; i < 4; ++i)
            af[i] = *reinterpret_cast<const short8*>(&as[(q * 128 + wm * 64 + i * 16 + m) * 8]);
        #pragma unroll
        for (int jn = 0; jn < 4; ++jn)
            bf[jn] = *reinterpret_cast<const short8*>(&bs[(q * 128 + wn * 64 + jn * 16 + m) * 8]);
        #pragma unroll
        for (int i = 0; i < 4; ++i)
            #pragma unroll
            for (int jn = 0; jn < 4; ++jn)
                acc[i][jn] = __builtin_amdgcn_mfma_f32_16x16x32_bf16(af[i], bf[jn], acc[i][jn], 0, 0, 0);
        __syncthreads();
    }

    // epilogue: C/D layout col = lane&15, row = (lane>>4)*4 + reg
    #pragma unroll
    for (int jn = 0; jn < 4; ++jn) {
        int col = col0 + wn * 64 + jn * 16 + m;
        float bj = bias[col];
        #pragma unroll
        for (int i = 0; i < 4; ++i) {
            int rowb = row0 + wm * 64 + i * 16 + q * 4;
            #pragma unroll
            for (int r = 0; r < 4; ++r) {
                float v = acc[i][jn][r] + bj;
                if (relu) v = fmaxf(v, 0.f);
                C[(size_t)(rowb + r) * 256 + col] = f2b(v);
            }
        }
    }
}

// ---------------- fused pool + MLP head: one block per graph ----------------
__global__ __launch_bounds__(256) void pool_mlp_kernel(
    const unsigned short* __restrict__ h, const int* __restrict__ batch,
    const float* __restrict__ Wm1, const float* __restrict__ bm1,
    const float* __restrict__ Wm2, const float* __restrict__ bm2,
    float* __restrict__ out)
{
    __shared__ float p[HID];
    __shared__ float red[HID];
    __shared__ int se[2];
    const int g = blockIdx.x, t = threadIdx.x;
    if (t < 2) {       // boundaries via binary search (batch is sorted)
        int target = g + t;
        int lo = 0, hi = N_NODES;
        while (lo < hi) { int mid = (lo + hi) >> 1; if (batch[mid] < target) lo = mid + 1; else hi = mid; }
        se[t] = lo;
    }
    __syncthreads();
    const int s = se[0], e = se[1];
    float acc = 0.f;
    for (int n = s; n < e; ++n) acc += b2f_lo((unsigned)h[(size_t)n * HID + t]);
    p[t] = acc / fmaxf((float)(e - s), 1.0f);
    __syncthreads();
    float a2 = bm1[t];
    for (int k = 0; k < HID; ++k) a2 = fmaf(p[k], Wm1[k * HID + t], a2);
    red[t] = fmaxf(a2, 0.f) * Wm2[t];
    __syncthreads();
    for (int o = 128; o > 0; o >>= 1) {
        if (t < o) red[t] += red[t + o];
        __syncthreads();
    }
    if (t == 0) out[g] = red[0] + bm2[0];
}

// ---------------- launch ----------------
extern "C" void kernel_launch(void* const* d_in, const int* in_sizes, int n_in,
                              void* d_out, int out_size, void* d_ws, size_t ws_size,
                              hipStream_t stream) {
    const float* x    = (const float*)d_in[0];
    const int*   ei   = (const int*)d_in[1];
    const int*   batch= (const int*)d_in[2];
    const float* W0   = (const float*)d_in[3];
    const float* b0   = (const float*)d_in[4];
    const float* W1   = (const float*)d_in[5];
    const float* b1   = (const float*)d_in[6];
    const float* W2   = (const float*)d_in[7];
    const float* b2   = (const float*)d_in[8];
    const float* Wm1  = (const float*)d_in[9];
    const float* bm1  = (const float*)d_in[10];
    const float* Wm2  = (const float*)d_in[11];
    const float* bm2  = (const float*)d_in[12];
    float* out = (float*)d_out;

    char* ws = (char*)d_ws;
    size_t off = 0;
    auto alloc = [&](size_t bytes) -> void* {
        void* p = ws + off;
        off += (bytes + 255) & ~(size_t)255;
        return p;
    };
    int*   deg       = (int*)  alloc((size_t)N_NODES * 4);
    float* dis       = (float*)alloc((size_t)N_NODES * 4);
    int*   row_start = (int*)  alloc((size_t)(N_NODES + 1) * 4);
    int*   cursor    = (int*)  alloc((size_t)N_NODES * 4);
    int*   bsum      = (int*)  alloc((size_t)64 * 4);
    int2*  csr       = (int2*) alloc((size_t)N_EDGES * 8);
    unsigned short* x_bf = (unsigned short*)alloc((size_t)N_NODES * F_IN * 2);
    unsigned short* Wt0  = (unsigned short*)alloc((size_t)F_IN * HID * 2);
    unsigned short* Wt1  = (unsigned short*)alloc((size_t)HID * HID * 2);
    unsigned short* Wt2  = (unsigned short*)alloc((size_t)HID * HID * 2);
    unsigned short* bufA = (unsigned short*)alloc((size_t)NPAD * HID * 2);
    unsigned short* bufB = (unsigned short*)alloc((size_t)NPAD * HID * 2);

    const int* src = ei;
    const int* dst = ei + N_EDGES;
    const int NB = (N_NODES + 1023) / 1024;   // 49

    hipMemsetAsync(deg, 0, (size_t)N_NODES * 4, stream);
    prep_kernel        <<<10015, 256, 0, stream>>>(dst, deg, x, x_bf, W0, W1, W2, Wt0, Wt1, Wt2);
    block_sum_dis_kernel<<<NB, 256, 0, stream>>>(deg, bsum, dis, N_NODES);
    scan_bsum_kernel   <<<1, 64, 0, stream>>>(bsum, NB);
    scan_local_kernel  <<<NB, 256, 0, stream>>>(deg, bsum, row_start, cursor, N_NODES);
    fill_csr           <<<(N_EDGES + 255) / 256, 256, 0, stream>>>(src, dst, dis, cursor, csr);

    dim3 ggrid(NPAD / 128, 2);

    agg_bf16<F_IN><<<(N_NODES + 3) / 4, 256, 0, stream>>>(x_bf, row_start, csr, dis, bufA);
    gemm_mfma<F_IN><<<ggrid, 256, 0, stream>>>(bufA, Wt0, b0, bufB, 1);

    agg_bf16<HID><<<(N_NODES + 3) / 4, 256, 0, stream>>>(bufB, row_start, csr, dis, bufA);
    gemm_mfma<HID><<<ggrid, 256, 0, stream>>>(bufA, Wt1, b1, bufB, 1);

    agg_bf16<HID><<<(N_NODES + 3) / 4, 256, 0, stream>>>(bufB, row_start, csr, dis, bufA);
    gemm_mfma<HID><<<ggrid, 256, 0, stream>>>(bufA, Wt2, b2, bufB, 1);

    pool_mlp_kernel<<<N_GRAPHS, HID, 0, stream>>>(bufB, batch, Wm1, bm1, Wm2, bm2, out);
}

// Round 4
// 430.883 us; speedup vs baseline: 1.9602x; 1.0115x over previous
//
#include <hip/hip_runtime.h>

// ---------------- problem constants ----------------
constexpr int N_NODES  = 50000;
constexpr int N_EDGES  = 800000;
constexpr int N_GRAPHS = 512;
constexpr int F_IN     = 128;
constexpr int HID      = 256;
constexpr int NPAD     = 50048;   // 391*128 padded rows

typedef short short8 __attribute__((ext_vector_type(8)));
typedef float f32x4  __attribute__((ext_vector_type(4)));

// bf16 helpers (raw ushort storage; RNE rounding)
__device__ __forceinline__ unsigned short f2b(float f) {
    unsigned u = __float_as_uint(f);
    u += 0x7fffu + ((u >> 16) & 1u);
    return (unsigned short)(u >> 16);
}
__device__ __forceinline__ float b2f_lo(unsigned u) { return __uint_as_float(u << 16); }
__device__ __forceinline__ float b2f_hi(unsigned u) { return __uint_as_float(u & 0xffff0000u); }

// ---------------- fused prep: deg histogram + x->bf16 + weights -> B-fragment layout ----------------
// Wt_frag short index: half*(K*128) + ((k>>3)*128 + (n&127))*8 + (k&7), half = n>>7
__global__ __launch_bounds__(256) void prep_kernel(
    const int* __restrict__ dst, int* __restrict__ deg,
    const float* __restrict__ x, unsigned short* __restrict__ x_bf,
    const float* __restrict__ W0, const float* __restrict__ W1, const float* __restrict__ W2,
    unsigned short* __restrict__ Wt0, unsigned short* __restrict__ Wt1, unsigned short* __restrict__ Wt2)
{
    const int b = blockIdx.x, t = threadIdx.x;
    if (b < 3125) {
        int e = b * 256 + t;                       // 3125*256 == 800000
        atomicAdd(&deg[dst[e]], 1);
    } else if (b < 9375) {
        int i = (b - 3125) * 256 + t;              // 6250*256 == 1.6M float4
        float4 v = *reinterpret_cast<const float4*>(x + (size_t)i * 4);
        unsigned r0 = (unsigned)f2b(v.x) | ((unsigned)f2b(v.y) << 16);
        unsigned r1 = (unsigned)f2b(v.z) | ((unsigned)f2b(v.w) << 16);
        *reinterpret_cast<uint2*>(x_bf + (size_t)i * 4) = make_uint2(r0, r1);
    } else {
        int i = (b - 9375) * 256 + t;              // 640*256 == 163840
        const float* W; unsigned short* Wt; int K; int j;
        if (i < 32768)      { W = W0; Wt = Wt0; K = 128; j = i; }
        else if (i < 98304) { W = W1; Wt = Wt1; K = 256; j = i - 32768; }
        else                { W = W2; Wt = Wt2; K = 256; j = i - 98304; }
        int k = j >> 8, n = j & 255;
        int idx = (n >> 7) * (K * 128) + (((k >> 3) * 128 + (n & 127)) << 3) + (k & 7);
        Wt[idx] = f2b(W[j]);
    }
}

// ---------------- parallel scan (3 kernels) + dis fused ----------------
__global__ void block_sum_dis_kernel(const int* __restrict__ deg, int* __restrict__ bsum,
                                     float* __restrict__ dis, int n) {
    __shared__ int sm[256];
    int t = threadIdx.x, base = blockIdx.x * 1024;
    int s = 0;
    #pragma unroll
    for (int i = 0; i < 4; ++i) {
        int idx = base + t + i * 256;
        if (idx < n) { int d = deg[idx]; s += d; dis[idx] = rsqrtf((float)d + 1.0f); }
    }
    sm[t] = s; __syncthreads();
    for (int o = 128; o > 0; o >>= 1) { if (t < o) sm[t] += sm[t + o]; __syncthreads(); }
    if (t == 0) bsum[blockIdx.x] = sm[0];
}

__global__ void scan_bsum_kernel(int* __restrict__ bsum, int nb) {   // 1 block, 64 threads
    __shared__ int sm[64];
    int t = threadIdx.x;
    int v = (t < nb) ? bsum[t] : 0;
    sm[t] = v; __syncthreads();
    for (int o = 1; o < 64; o <<= 1) {
        int a = (t >= o) ? sm[t - o] : 0; __syncthreads();
        sm[t] += a; __syncthreads();
    }
    if (t < nb) bsum[t] = sm[t] - v;   // exclusive
}

__global__ void scan_local_kernel(const int* __restrict__ deg, const int* __restrict__ bsum,
                                  int* __restrict__ row_start, int* __restrict__ cursor, int n) {
    __shared__ int sm[256];
    int t = threadIdx.x, base = blockIdx.x * 1024;
    int idx0 = base + t * 4;
    int v[4], s = 0;
    #pragma unroll
    for (int i = 0; i < 4; ++i) { int id = idx0 + i; v[i] = (id < n) ? deg[id] : 0; s += v[i]; }
    sm[t] = s; __syncthreads();
    for (int o = 1; o < 256; o <<= 1) {
        int a = (t >= o) ? sm[t - o] : 0; __syncthreads();
        sm[t] += a; __syncthreads();
    }
    int excl = bsum[blockIdx.x] + sm[t] - s;
    #pragma unroll
    for (int i = 0; i < 4; ++i) {
        int id = idx0 + i;
        if (id < n) { row_start[id] = excl; cursor[id] = excl; }
        excl += v[i];
    }
    if (blockIdx.x == gridDim.x - 1 && t == 255) row_start[n] = excl;  // == N_EDGES
}

// ---------------- CSR scatter: entry = (src, w_bits) ----------------
__global__ void fill_csr(const int* __restrict__ src, const int* __restrict__ dst,
                         const float* __restrict__ dis, int* __restrict__ cursor,
                         int2* __restrict__ csr) {
    int e = blockIdx.x * blockDim.x + threadIdx.x;
    if (e >= N_EDGES) return;
    int s = src[e], d = dst[e];
    int pos = atomicAdd(&cursor[d], 1);
    float w = dis[s] * dis[d];
    csr[pos] = make_int2(s, __float_as_int(w));
}

// ---------------- aggregation: row-major bf16 gather -> MFMA-A-fragment bf16 output ----------------
// out chunk (16B) index: panel*(128*F/8) + fc*128 + (node&127)
template<int F>
__global__ __launch_bounds__(256) void agg_bf16(
    const unsigned short* __restrict__ hin, const int* __restrict__ row_start,
    const int2* __restrict__ csr, const float* __restrict__ dis,
    uint4* __restrict__ out4)
{
    constexpr int LPR  = F / 8;     // lanes per row: 32 (F=256) / 16 (F=128)
    constexpr int NSUB = 64 / LPR;  // subgroups per wave
    const int lane = threadIdx.x & 63;
    const int sub  = lane / LPR;
    const int fc   = lane % LPR;    // 16-byte feature chunk
    const int node = blockIdx.x * 4 + (threadIdx.x >> 6);
    if (node >= N_NODES) return;

    float acc[8];
    {   // self-loop term (sub 0 only)
        float dn = dis[node];
        float sw = (sub == 0) ? dn * dn : 0.0f;
        uint2 u2[2];
        *reinterpret_cast<uint4*>(u2) =
            *reinterpret_cast<const uint4*>(hin + (size_t)node * F + fc * 8);
        #pragma unroll
        for (int h = 0; h < 2; ++h) {
            acc[h * 4 + 0] = b2f_lo(u2[h].x) * sw;
            acc[h * 4 + 1] = b2f_hi(u2[h].x) * sw;
            acc[h * 4 + 2] = b2f_lo(u2[h].y) * sw;
            acc[h * 4 + 3] = b2f_hi(u2[h].y) * sw;
        }
    }

    int j = row_start[node] + sub;
    const int end = row_start[node + 1];
    for (; j + 3 * NSUB < end; j += 4 * NSUB) {
        int2 c[4];
        #pragma unroll
        for (int u = 0; u < 4; ++u) c[u] = csr[j + u * NSUB];
        #pragma unroll
        for (int u = 0; u < 4; ++u) {
            float w = __int_as_float(c[u].y);
            uint2 g[2];
            *reinterpret_cast<uint4*>(g) =
                *reinterpret_cast<const uint4*>(hin + (size_t)c[u].x * F + fc * 8);
            #pragma unroll
            for (int h = 0; h < 2; ++h) {
                acc[h * 4 + 0] = fmaf(b2f_lo(g[h].x), w, acc[h * 4 + 0]);
                acc[h * 4 + 1] = fmaf(b2f_hi(g[h].x), w, acc[h * 4 + 1]);
                acc[h * 4 + 2] = fmaf(b2f_lo(g[h].y), w, acc[h * 4 + 2]);
                acc[h * 4 + 3] = fmaf(b2f_hi(g[h].y), w, acc[h * 4 + 3]);
            }
        }
    }
    for (; j < end; j += NSUB) {
        int2 c0 = csr[j];
        float w = __int_as_float(c0.y);
        uint2 g[2];
        *reinterpret_cast<uint4*>(g) =
            *reinterpret_cast<const uint4*>(hin + (size_t)c0.x * F + fc * 8);
        #pragma unroll
        for (int h = 0; h < 2; ++h) {
            acc[h * 4 + 0] = fmaf(b2f_lo(g[h].x), w, acc[h * 4 + 0]);
            acc[h * 4 + 1] = fmaf(b2f_hi(g[h].x), w, acc[h * 4 + 1]);
            acc[h * 4 + 2] = fmaf(b2f_lo(g[h].y), w, acc[h * 4 + 2]);
            acc[h * 4 + 3] = fmaf(b2f_hi(g[h].y), w, acc[h * 4 + 3]);
        }
    }

    #pragma unroll
    for (int k = 0; k < 8; ++k) {
        #pragma unroll
        for (int off = LPR; off < 64; off <<= 1)
            acc[k] += __shfl_xor(acc[k], off, 64);
    }

    if (sub == 0) {
        uint2 r[2];
        #pragma unroll
        for (int h = 0; h < 2; ++h) {
            r[h].x = (unsigned)f2b(acc[h * 4 + 0]) | ((unsigned)f2b(acc[h * 4 + 1]) << 16);
            r[h].y = (unsigned)f2b(acc[h * 4 + 2]) | ((unsigned)f2b(acc[h * 4 + 3]) << 16);
        }
        // fragment-layout store: adjacent waves (node&127 consecutive) fill 64B lines
        int chunk = (node >> 7) * (128 * (F / 8)) + fc * 128 + (node & 127);
        out4[chunk] = *reinterpret_cast<uint4*>(r);
    }
}

// ---------------- MFMA GEMM, fragment-direct A, full weight-half resident in LDS ----------------
// A in fragment layout [panel][kchunk][row][8]; Wt_frag in [half][kchunk][col][8].
// grid (NPAD/128, 2); 256 threads = 4 waves (2x2 of 64x64). One barrier total.
template<int K>
__global__ __launch_bounds__(256) void gemm_frag(
    const uint4* __restrict__ A4,
    const unsigned short* __restrict__ Wt_frag,
    const float* __restrict__ bias,
    unsigned short* __restrict__ C,
    int relu)
{
    __shared__ __align__(16) unsigned short Bs[K * 128];   // 64 KB (K=256) / 32 KB (K=128)
    const int t    = threadIdx.x;
    const int lane = t & 63;
    const int w    = t >> 6;
    const int wm   = w & 1, wn = w >> 1;
    const int q    = lane >> 4, m = lane & 15;
    const int panel = blockIdx.x;
    const int col0  = blockIdx.y * 128;

    // stage the whole 128-col weight half: contiguous, coalesced, conflict-free
    {
        const uint4* src4 = reinterpret_cast<const uint4*>(Wt_frag + blockIdx.y * (K * 128));
        uint4* dst4 = reinterpret_cast<uint4*>(Bs);
        #pragma unroll
        for (int it = 0; it < K / 16; ++it)
            dst4[it * 256 + t] = src4[it * 256 + t];
    }
    __syncthreads();

    f32x4 acc[4][4] = {};
    const int abase = panel * (128 * (K / 8));

    #pragma unroll
    for (int kb = 0; kb < K / 32; ++kb) {
        short8 af[4], bf[4];
        #pragma unroll
        for (int i = 0; i < 4; ++i) {
            uint4 v = A4[abase + (kb * 4 + q) * 128 + wm * 64 + i * 16 + m];
            af[i] = *reinterpret_cast<short8*>(&v);
        }
        #pragma unroll
        for (int jn = 0; jn < 4; ++jn)
            bf[jn] = *reinterpret_cast<const short8*>(&Bs[((kb * 4 + q) * 128 + wn * 64 + jn * 16 + m) * 8]);
        #pragma unroll
        for (int i = 0; i < 4; ++i)
            #pragma unroll
            for (int jn = 0; jn < 4; ++jn)
                acc[i][jn] = __builtin_amdgcn_mfma_f32_16x16x32_bf16(af[i], bf[jn], acc[i][jn], 0, 0, 0);
    }

    // epilogue: C/D layout col = lane&15, row = (lane>>4)*4 + reg; row-major bf16 out
    #pragma unroll
    for (int jn = 0; jn < 4; ++jn) {
        int col = col0 + wn * 64 + jn * 16 + m;
        float bj = bias[col];
        #pragma unroll
        for (int i = 0; i < 4; ++i) {
            int rowb = panel * 128 + wm * 64 + i * 16 + q * 4;
            #pragma unroll
            for (int r = 0; r < 4; ++r) {
                float v = acc[i][jn][r] + bj;
                if (relu) v = fmaxf(v, 0.f);
                C[(size_t)(rowb + r) * 256 + col] = f2b(v);
            }
        }
    }
}

// ---------------- fused pool + MLP head ----------------
__global__ __launch_bounds__(256) void pool_mlp_kernel(
    const unsigned short* __restrict__ h, const int* __restrict__ batch,
    const float* __restrict__ Wm1, const float* __restrict__ bm1,
    const float* __restrict__ Wm2, const float* __restrict__ bm2,
    float* __restrict__ out)
{
    __shared__ float p[HID];
    __shared__ float red[HID];
    __shared__ int se[2];
    const int g = blockIdx.x, t = threadIdx.x;
    if (t < 2) {
        int target = g + t;
        int lo = 0, hi = N_NODES;
        while (lo < hi) { int mid = (lo + hi) >> 1; if (batch[mid] < target) lo = mid + 1; else hi = mid; }
        se[t] = lo;
    }
    __syncthreads();
    const int s = se[0], e = se[1];
    float acc = 0.f;
    for (int n = s; n < e; ++n) acc += b2f_lo((unsigned)h[(size_t)n * HID + t]);
    p[t] = acc / fmaxf((float)(e - s), 1.0f);
    __syncthreads();
    float a2 = bm1[t];
    for (int k = 0; k < HID; ++k) a2 = fmaf(p[k], Wm1[k * HID + t], a2);
    red[t] = fmaxf(a2, 0.f) * Wm2[t];
    __syncthreads();
    for (int o = 128; o > 0; o >>= 1) {
        if (t < o) red[t] += red[t + o];
        __syncthreads();
    }
    if (t == 0) out[g] = red[0] + bm2[0];
}

// ---------------- launch ----------------
extern "C" void kernel_launch(void* const* d_in, const int* in_sizes, int n_in,
                              void* d_out, int out_size, void* d_ws, size_t ws_size,
                              hipStream_t stream) {
    const float* x    = (const float*)d_in[0];
    const int*   ei   = (const int*)d_in[1];
    const int*   batch= (const int*)d_in[2];
    const float* W0   = (const float*)d_in[3];
    const float* b0   = (const float*)d_in[4];
    const float* W1   = (const float*)d_in[5];
    const float* b1   = (const float*)d_in[6];
    const float* W2   = (const float*)d_in[7];
    const float* b2   = (const float*)d_in[8];
    const float* Wm1  = (const float*)d_in[9];
    const float* bm1  = (const float*)d_in[10];
    const float* Wm2  = (const float*)d_in[11];
    const float* bm2  = (const float*)d_in[12];
    float* out = (float*)d_out;

    char* ws = (char*)d_ws;
    size_t off = 0;
    auto alloc = [&](size_t bytes) -> void* {
        void* p = ws + off;
        off += (bytes + 255) & ~(size_t)255;
        return p;
    };
    int*   deg       = (int*)  alloc((size_t)N_NODES * 4);
    float* dis       = (float*)alloc((size_t)N_NODES * 4);
    int*   row_start = (int*)  alloc((size_t)(N_NODES + 1) * 4);
    int*   cursor    = (int*)  alloc((size_t)N_NODES * 4);
    int*   bsum      = (int*)  alloc((size_t)64 * 4);
    int2*  csr       = (int2*) alloc((size_t)N_EDGES * 8);
    unsigned short* x_bf = (unsigned short*)alloc((size_t)N_NODES * F_IN * 2);
    unsigned short* Wt0  = (unsigned short*)alloc((size_t)F_IN * HID * 2);
    unsigned short* Wt1  = (unsigned short*)alloc((size_t)HID * HID * 2);
    unsigned short* Wt2  = (unsigned short*)alloc((size_t)HID * HID * 2);
    unsigned short* bufA = (unsigned short*)alloc((size_t)NPAD * HID * 2);
    unsigned short* bufB = (unsigned short*)alloc((size_t)NPAD * HID * 2);

    const int* src = ei;
    const int* dst = ei + N_EDGES;
    const int NB = (N_NODES + 1023) / 1024;   // 49

    hipMemsetAsync(deg, 0, (size_t)N_NODES * 4, stream);
    prep_kernel         <<<10015, 256, 0, stream>>>(dst, deg, x, x_bf, W0, W1, W2, Wt0, Wt1, Wt2);
    block_sum_dis_kernel<<<NB, 256, 0, stream>>>(deg, bsum, dis, N_NODES);
    scan_bsum_kernel    <<<1, 64, 0, stream>>>(bsum, NB);
    scan_local_kernel   <<<NB, 256, 0, stream>>>(deg, bsum, row_start, cursor, N_NODES);
    fill_csr            <<<(N_EDGES + 255) / 256, 256, 0, stream>>>(src, dst, dis, cursor, csr);

    dim3 ggrid(NPAD / 128, 2);

    // layer 0: agg (row-major in, fragment out) -> fragment-direct GEMM (row-major out)
    agg_bf16<F_IN><<<(N_NODES + 3) / 4, 256, 0, stream>>>(x_bf, row_start, csr, dis, (uint4*)bufA);
    gemm_frag<F_IN><<<ggrid, 256, 0, stream>>>((const uint4*)bufA, Wt0, b0, bufB, 1);

    agg_bf16<HID><<<(N_NODES + 3) / 4, 256, 0, stream>>>(bufB, row_start, csr, dis, (uint4*)bufA);
    gemm_frag<HID><<<ggrid, 256, 0, stream>>>((const uint4*)bufA, Wt1, b1, bufB, 1);

    agg_bf16<HID><<<(N_NODES + 3) / 4, 256, 0, stream>>>(bufB, row_start, csr, dis, (uint4*)bufA);
    gemm_frag<HID><<<ggrid, 256, 0, stream>>>((const uint4*)bufA, Wt2, b2, bufB, 1);

    pool_mlp_kernel<<<N_GRAPHS, HID, 0, stream>>>(bufB, batch, Wm1, bm1, Wm2, bm2, out);
}